// Round 6
// baseline (312.740 us; speedup 1.0000x reference)
//
#include <hip/hip_runtime.h>
#include <hip/hip_bf16.h>

typedef __hip_bfloat16 bf16;
typedef __attribute__((ext_vector_type(8))) short bf16x8;   // 8 bf16 = 4 VGPRs (MFMA A/B frag)
typedef __attribute__((ext_vector_type(4))) float f32x4;    // MFMA C/D frag
typedef unsigned int u32;
typedef unsigned short u16;

#define MFMA(a,b,c) __builtin_amdgcn_mfma_f32_16x16x32_bf16((a),(b),(c),0,0,0)

__device__ __forceinline__ u16 f32_to_bf16_rtne(float f) {
  u32 b = __builtin_bit_cast(u32, f);
  b += 0x7FFFu + ((b >> 16) & 1u);
  return (u16)(b >> 16);
}
__device__ __forceinline__ u32 pk2bf(float a, float b) {
  u32 ua = __builtin_bit_cast(u32, a); ua += 0x7FFFu + ((ua >> 16) & 1u);
  u32 ub = __builtin_bit_cast(u32, b); ub += 0x7FFFu + ((ub >> 16) & 1u);
  return __builtin_amdgcn_perm(ub, ua, 0x07060302u);
}
__device__ __forceinline__ u32 pk2bf_rtz(float a, float b) {
  return __builtin_amdgcn_perm(__builtin_bit_cast(u32, b),
                               __builtin_bit_cast(u32, a), 0x07060302u);
}
__device__ __forceinline__ uint4 cvt8(uint4 lo, uint4 hi) {
  const float4 fl = __builtin_bit_cast(float4, lo);
  const float4 fh = __builtin_bit_cast(float4, hi);
  uint4 r;
  r.x = pk2bf(fl.x, fl.y); r.y = pk2bf(fl.z, fl.w);
  r.z = pk2bf(fh.x, fh.y); r.w = pk2bf(fh.z, fh.w);
  return r;
}

// async global->LDS DMA, 16B/lane; LDS dest = wave-uniform base + lane*16B
typedef const __attribute__((address_space(1))) void* gas_ptr;
typedef __attribute__((address_space(3))) void* las_ptr;
__device__ __forceinline__ void gload_lds16(const void* g, void* l) {
  __builtin_amdgcn_global_load_lds((gas_ptr)g, (las_ptr)l, 16, 0, 0);
}

static constexpr float SL2E = 0.125f * 1.44269504f;  // 1/sqrt(dh) * log2(e)

// ---------------------------------------------------------------------------
// f32 -> bf16 casts: W q/k/v/o and x.
// ---------------------------------------------------------------------------
__global__ __launch_bounds__(256)
void cast_all(const float* __restrict__ wq, const float* __restrict__ wk,
              const float* __restrict__ wv, const float* __restrict__ wo,
              const float* __restrict__ x,
              u16* __restrict__ wqkv, u16* __restrict__ wob,
              u16* __restrict__ xb) {
  const size_t DD8 = (size_t)1024 * 1024 / 8;
  if (blockIdx.x < 2048) {
    const int m = blockIdx.x >> 9;
    const size_t i = ((size_t)(blockIdx.x & 511)) * 256 + threadIdx.x;
    const float* src = (m == 0) ? wq : (m == 1) ? wk : (m == 2) ? wv : wo;
    u16* dst = (m < 3) ? (wqkv + (size_t)m * DD8 * 8) : wob;
    const float4* s = (const float4*)src + i * 2;
    ((uint4*)dst)[i] = cvt8(__builtin_bit_cast(uint4, s[0]),
                            __builtin_bit_cast(uint4, s[1]));
  } else {
    const size_t i = ((size_t)(blockIdx.x - 2048)) * 256 + threadIdx.x;
    const float4* s = (const float4*)x + i * 2;
    ((uint4*)xb)[i] = cvt8(__builtin_bit_cast(uint4, s[0]),
                           __builtin_bit_cast(uint4, s[1]));
  }
}

// ---------------------------------------------------------------------------
// 2-phase GEMM (R4 structure, best measured: 75.4 us QKV), BM=128 x BN=256,
// BK=64, 512 thr = 8 waves (2M x 4N), per-wave 64x64, acc[4][4].
// LDS 96 KiB (A 32K + B 64K, double-buffered).  vmcnt(4) counted at tile
// boundary; never drained to 0 mid-loop.
// ---------------------------------------------------------------------------
template <int MODE>
__global__ __launch_bounds__(512, 2)
void gemm8p(const bf16* __restrict__ A, const bf16* __restrict__ W,
            const float* __restrict__ b0, const float* __restrict__ b1,
            const float* __restrict__ b2, void* __restrict__ o0,
            void* __restrict__ o1, void* __restrict__ o2,
            int M, int N, int K)
{
  __shared__ __align__(16) bf16 AsB[2][128 * 64];
  __shared__ __align__(16) bf16 BsB[2][256 * 64];

  const int nwg = gridDim.x * gridDim.y;   // 768 or 256 (both %8 == 0)
  const int raw = blockIdx.y * gridDim.x + blockIdx.x;
  const int vwg = (raw & 7) * (nwg >> 3) + (raw >> 3);
  const int NT  = gridDim.y;               // N-tiles (12 or 4)
  const int bx  = vwg / NT, by = vwg - bx * NT;
  const int m0  = bx * 128, n0 = by * 256;

  const int tid  = threadIdx.x;
  const int wv   = tid >> 6, lane = tid & 63;
  const int quad = lane >> 4, l16 = lane & 15;
  const int wm   = wv >> 2, wn = wv & 3;   // wave grid 2M x 4N
  const int r7   = l16 & 7;

  const int rr = tid >> 3, g = tid & 7;
  const int sg8 = (g ^ (rr & 7)) * 8;      // pre-swizzled source granule
  const bf16* aS = A + (size_t)(m0 + rr) * K + sg8;
  const bf16* wS = W + (size_t)(n0 + rr) * K + sg8;
  const int ldstW = wv * 512;              // wave-uniform LDS offset in chunk

#define STA8(buf, kt) do { \
    gload_lds16(aS + (size_t)(kt) * 64,                      &AsB[buf][ldstW]); \
    gload_lds16(aS + (size_t)64 * K + (size_t)(kt) * 64,     &AsB[buf][4096 + ldstW]); \
  } while (0)
#define STB8(buf, kt) do { \
    gload_lds16(wS + (size_t)(kt) * 64,                      &BsB[buf][ldstW]); \
    gload_lds16(wS + (size_t)64 * K + (size_t)(kt) * 64,     &BsB[buf][4096 + ldstW]); \
    gload_lds16(wS + (size_t)128 * K + (size_t)(kt) * 64,    &BsB[buf][8192 + ldstW]); \
    gload_lds16(wS + (size_t)192 * K + (size_t)(kt) * 64,    &BsB[buf][12288 + ldstW]); \
  } while (0)

  int aoff[4], boff[4];
#pragma unroll
  for (int mt = 0; mt < 4; ++mt) aoff[mt] = (wm * 64 + mt * 16 + l16) * 64;
#pragma unroll
  for (int nt = 0; nt < 4; ++nt) boff[nt] = (wn * 64 + nt * 16 + l16) * 64;
  const int k0o = (quad ^ r7) * 8;
  const int k1o = ((4 + quad) ^ r7) * 8;

  f32x4 acc[4][4] = {};
  bf16x8 bfr[4][2], afr[2][2];

  const int nk = K >> 6;   // 16

  // prologue: A(0), B(0) landed; B(1) in flight
  STA8(0, 0);
  STB8(0, 0);
  STB8(1, 1);
  asm volatile("s_waitcnt vmcnt(4)\n\ts_barrier" ::: "memory");

  for (int t = 0; t < nk; ++t) {
    const int c = t & 1;
    const bf16* Ac = AsB[c];
    const bf16* Bc = BsB[c];

    // phase 1: all-B + A-lo; stage A(t+1); MFMA mt0-1
#pragma unroll
    for (int nt = 0; nt < 4; ++nt) {
      bfr[nt][0] = *(const bf16x8*)(Bc + boff[nt] + k0o);
      bfr[nt][1] = *(const bf16x8*)(Bc + boff[nt] + k1o);
    }
#pragma unroll
    for (int mt = 0; mt < 2; ++mt) {
      afr[mt][0] = *(const bf16x8*)(Ac + aoff[mt] + k0o);
      afr[mt][1] = *(const bf16x8*)(Ac + aoff[mt] + k1o);
    }
    if (t + 1 < nk) STA8((t + 1) & 1, t + 1);
    asm volatile("s_barrier" ::: "memory");
    __builtin_amdgcn_s_setprio(1);
#pragma unroll
    for (int mt = 0; mt < 2; ++mt)
#pragma unroll
      for (int nt = 0; nt < 4; ++nt) {
        acc[mt][nt] = MFMA(afr[mt][0], bfr[nt][0], acc[mt][nt]);
        acc[mt][nt] = MFMA(afr[mt][1], bfr[nt][1], acc[mt][nt]);
      }
    __builtin_amdgcn_s_setprio(0);
    asm volatile("s_waitcnt lgkmcnt(0)\n\ts_barrier" ::: "memory");

    // phase 2: A-hi; stage B(t+2); MFMA mt2-3
#pragma unroll
    for (int mt = 0; mt < 2; ++mt) {
      afr[mt][0] = *(const bf16x8*)(Ac + aoff[mt + 2] + k0o);
      afr[mt][1] = *(const bf16x8*)(Ac + aoff[mt + 2] + k1o);
    }
    if (t + 2 < nk) STB8(c, t + 2);
    asm volatile("s_barrier" ::: "memory");
    __builtin_amdgcn_s_setprio(1);
#pragma unroll
    for (int mt = 0; mt < 2; ++mt)
#pragma unroll
      for (int nt = 0; nt < 4; ++nt) {
        acc[mt + 2][nt] = MFMA(afr[mt][0], bfr[nt][0], acc[mt + 2][nt]);
        acc[mt + 2][nt] = MFMA(afr[mt][1], bfr[nt][1], acc[mt + 2][nt]);
      }
    __builtin_amdgcn_s_setprio(0);
    if (t + 1 < nk) {
      if (t + 2 < nk)
        asm volatile("s_waitcnt vmcnt(4) lgkmcnt(0)\n\ts_barrier" ::: "memory");
      else
        asm volatile("s_waitcnt vmcnt(0) lgkmcnt(0)\n\ts_barrier" ::: "memory");
    }
  }
#undef STA8
#undef STB8

  // epilogue: C/D layout col = lane&15, row = quad*4 + reg
  const int band = n0 >> 10;
  const float* bias = (band == 0) ? b0 : (band == 1) ? b1 : b2;
#pragma unroll
  for (int nt = 0; nt < 4; ++nt) {
    const int col = n0 + wn * 64 + nt * 16 + l16;
    const int cl  = col & 1023;
    const float bv = bias[cl];
#pragma unroll
    for (int mt = 0; mt < 4; ++mt) {
      const int rbase = m0 + wm * 64 + mt * 16 + quad * 4;
      if (MODE == 1) {
#pragma unroll
        for (int r = 0; r < 4; ++r)
          ((float*)o0)[(size_t)(rbase + r) * N + col] = acc[mt][nt][r] + bv;
      } else if (band == 2) {
        const int hh = cl >> 6, dd = cl & 63;
        const int bb = rbase >> 12, tl = rbase & 4095;
        u16* dst = (u16*)o2 + ((size_t)((bb * 16 + hh) * 64 + dd)) * 4096 + tl;
        uint2 pk;
        pk.x = pk2bf(acc[mt][nt][0] + bv, acc[mt][nt][1] + bv);
        pk.y = pk2bf(acc[mt][nt][2] + bv, acc[mt][nt][3] + bv);
        *(uint2*)dst = pk;
      } else {
        u16* dst = (u16*)((band == 0) ? o0 : o1);
        const float sc = (band == 0) ? SL2E : 1.0f;
#pragma unroll
        for (int r = 0; r < 4; ++r)
          dst[(size_t)(rbase + r) * 1024 + cl] =
              f32_to_bf16_rtne((acc[mt][nt][r] + bv) * sc);
      }
    }
  }
}

// ---------------------------------------------------------------------------
// Sliding-window attention, S^T formulation, fixed-max softmax, NO LDS:
// K and V MFMA fragments are loaded DIRECTLY from global (L2/L3-resident;
// KV slab per (b,c,h) is 256 KB, reused 8x across blocks).  The old LDS
// K-row permutation `sig` (which makes P->PV packing line up without any
// cross-lane shuffle) is folded into the per-lane global row index:
//   key = kstart + t*64 + s_l + {0,32,4,36}[kt],
//   s_l = ((l16>>3)<<4) | (((l16>>2)&1)<<3) | (l16&3)
// -- algebra verified to reproduce the LDS order exactly, so the softmax /
// pf-packing / PV pipeline is unchanged.  Waves are fully independent (no
// barriers).  Pipeline: issue V(t) loads, QK^T (hides V latency), softmax,
// issue K(t+1) loads, PV (hides K latency).
// Chunked XCD swizzle: 4 qt-blocks of one (b,c,h) land on the same XCD.
// ---------------------------------------------------------------------------
__global__ __launch_bounds__(256)
void attn_swin(const bf16* __restrict__ qb, const bf16* __restrict__ kb,
               const bf16* __restrict__ vtb, u16* __restrict__ ctx)
{
  // chunked XCD mapping: HW xcd = raw%8; virtual id groups 128 consecutive
  // vb per XCD; decode vb = (g<<2)|qt so same-KV blocks stay on one XCD.
  const int raw = blockIdx.x;
  const int vb  = (raw & 7) * 128 + (raw >> 3);
  const int qt  = vb & 3, g = vb >> 2;
  const int h   = g & 15, c = (g >> 4) & 7, b = g >> 7;

  const int tid  = threadIdx.x;
  const int w    = tid >> 6, lane = tid & 63;
  const int quad = lane >> 4, l16 = lane & 15;

  const int tq0  = c * 512 + qt * 128;
  const int hoff = h * 64;
  const int kstart = (c == 0) ? 0 : (c - 1) * 512;
  const int nkt    = (c == 0) ? 8 : 16;

  // ---- Q B-frags straight from global ----
  bf16x8 qf[2][2];
#pragma unroll
  for (int u = 0; u < 2; ++u) {
    const bf16* qr = qb + ((size_t)(b * 4096 + tq0 + w * 32 + u * 16 + l16)) * 1024 + hoff;
    qf[u][0] = *(const bf16x8*)(qr + quad * 8);
    qf[u][1] = *(const bf16x8*)(qr + 32 + quad * 8);
  }

  // ---- direct-global K/V fragment base pointers ----
  const int s_l = ((l16 >> 3) << 4) | (((l16 >> 2) & 1) << 3) | (l16 & 3);
  const bf16* kR = kb + ((size_t)(b * 4096 + kstart + s_l)) * 1024 + hoff + quad * 8;
  const bf16* vR = vtb + ((size_t)((b * 16 + h) * 64 + l16)) * 4096 + kstart + quad * 8;
  const int ktrow[4] = {0, 32, 4, 36};     // sig's kt contribution (rows)

  float l_i[2] = {0.f, 0.f};
  f32x4 o[2][4] = {};
  bf16x8 kf[4][2], vf[4][2];

  typedef union { u32 d[4]; bf16x8 v; } fragu;

  // preload K frags of tile 0
#pragma unroll
  for (int kt = 0; kt < 4; ++kt) {
    const bf16* kp = kR + (size_t)ktrow[kt] * 1024;
    kf[kt][0] = *(const bf16x8*)(kp);
    kf[kt][1] = *(const bf16x8*)(kp + 32);
  }
  kR += (size_t)64 * 1024;

  for (int t = 0; t < nkt; ++t) {
    // issue V(t) frag loads (consumed after softmax -> latency hidden by QK^T)
#pragma unroll
    for (int dt = 0; dt < 4; ++dt) {
      const bf16* vp = vR + (size_t)dt * 16 * 4096;
      vf[dt][0] = *(const bf16x8*)(vp);
      vf[dt][1] = *(const bf16x8*)(vp + 32);
    }
    vR += 64;

    // QK^T
    f32x4 s[2][4] = {};
#pragma unroll
    for (int kt = 0; kt < 4; ++kt) {
      s[0][kt] = MFMA(kf[kt][0], qf[0][0], s[0][kt]);
      s[0][kt] = MFMA(kf[kt][1], qf[0][1], s[0][kt]);
      s[1][kt] = MFMA(kf[kt][0], qf[1][0], s[1][kt]);
      s[1][kt] = MFMA(kf[kt][1], qf[1][1], s[1][kt]);
    }

    // prefetch K frags of t+1 (latency hidden by softmax + PV)
    if (t + 1 < nkt) {
#pragma unroll
      for (int kt = 0; kt < 4; ++kt) {
        const bf16* kp = kR + (size_t)ktrow[kt] * 1024;
        kf[kt][0] = *(const bf16x8*)(kp);
        kf[kt][1] = *(const bf16x8*)(kp + 32);
      }
      kR += (size_t)64 * 1024;
    }

    // softmax (fixed-max, exp2-domain; q pre-scaled by SL2E) + P packing
    fragu pf[2][2];
#pragma unroll
    for (int u = 0; u < 2; ++u) {
      float rs = 0.f;
#pragma unroll
      for (int kt = 0; kt < 4; ++kt)
#pragma unroll
        for (int r = 0; r < 4; ++r) {
          const float p = __builtin_amdgcn_exp2f(s[u][kt][r]);
          s[u][kt][r] = p;
          rs += p;
        }
      rs += __shfl_xor(rs, 16);
      rs += __shfl_xor(rs, 32);
      l_i[u] += rs;
#pragma unroll
      for (int hh = 0; hh < 2; ++hh)
#pragma unroll
        for (int dw = 0; dw < 4; ++dw) {
          const int kt = 2 * (dw >> 1) + hh, r0 = 2 * (dw & 1);
          pf[u][hh].d[dw] = pk2bf_rtz(s[u][kt][r0], s[u][kt][r0 + 1]);
        }
    }

    // PV
#pragma unroll
    for (int dt = 0; dt < 4; ++dt) {
      o[0][dt] = MFMA(vf[dt][0], pf[0][0].v, o[0][dt]);
      o[0][dt] = MFMA(vf[dt][1], pf[0][1].v, o[0][dt]);
      o[1][dt] = MFMA(vf[dt][0], pf[1][0].v, o[1][dt]);
      o[1][dt] = MFMA(vf[dt][1], pf[1][1].v, o[1][dt]);
    }
  }

  // ---- epilogue: O^T element (d = dt*16+quad*4+r, q = l16) ----
#pragma unroll
  for (int u = 0; u < 2; ++u) {
    const float inv = 1.0f / l_i[u];
    const int qrow = tq0 + w * 32 + u * 16 + l16;
    u16* crow = ctx + ((size_t)(b * 4096 + qrow)) * 1024 + hoff;
#pragma unroll
    for (int dt = 0; dt < 4; ++dt) {
      uint2 pk;
      pk.x = pk2bf(o[u][dt][0] * inv, o[u][dt][1] * inv);
      pk.y = pk2bf(o[u][dt][2] * inv, o[u][dt][3] * inv);
      *(uint2*)(crow + dt * 16 + quad * 4) = pk;
    }
  }
}

// ---------------------------------------------------------------------------
extern "C" void kernel_launch(void* const* d_in, const int* in_sizes, int n_in,
                              void* d_out, int out_size, void* d_ws, size_t ws_size,
                              hipStream_t stream) {
  const float* x  = (const float*)d_in[0];
  const float* Wq = (const float*)d_in[1];
  const float* bq = (const float*)d_in[2];
  const float* Wk = (const float*)d_in[3];
  const float* bk = (const float*)d_in[4];
  const float* Wv = (const float*)d_in[5];
  const float* bv = (const float*)d_in[6];
  const float* Wo = (const float*)d_in[7];
  const float* bo = (const float*)d_in[8];

  const size_t MD = (size_t)8192 * 1024;   // [B*L, D] elements
  const size_t DD = (size_t)1024 * 1024;   // [D, D] elements

  char* ws = (char*)d_ws;
  u16*  Wqkvb = (u16*)ws;                     ws += 3 * DD * 2;
  u16*  Wob   = (u16*)ws;                     ws += DD * 2;
  u16*  qbuf  = (u16*)ws;                     ws += MD * 2;
  u16*  kbuf  = (u16*)ws;                     ws += MD * 2;
  u16*  vtb   = (u16*)ws;                     ws += MD * 2;
  u16*  ctx   = (u16*)ws;                     // + MD*2  (~72 MB total)

  // xb aliases ctx: dead after the QKV GEMM; attn writes ctx afterwards.
  u16* xb = ctx;

  cast_all<<<dim3(6144), dim3(256), 0, stream>>>(Wq, Wk, Wv, Wo, x,
                                                 Wqkvb, Wob, xb);

  gemm8p<0><<<dim3(64, 12), dim3(512), 0, stream>>>(
      (const bf16*)xb, (const bf16*)Wqkvb, bq, bk, bv,
      qbuf, kbuf, vtb, 8192, 3072, 1024);

  attn_swin<<<dim3(1024), dim3(256), 0, stream>>>(
      (const bf16*)qbuf, (const bf16*)kbuf, (const bf16*)vtb, ctx);

  gemm8p<1><<<dim3(64, 4), dim3(512), 0, stream>>>(
      (const bf16*)ctx, (const bf16*)Wob, bo, bo, bo,
      d_out, nullptr, nullptr, 8192, 1024, 1024);
}

// Round 7
// 240.151 us; speedup vs baseline: 1.3023x; 1.3023x over previous
//
#include <hip/hip_runtime.h>
#include <hip/hip_bf16.h>

typedef __hip_bfloat16 bf16;
typedef __attribute__((ext_vector_type(8))) short bf16x8;   // 8 bf16 = 4 VGPRs (MFMA A/B frag)
typedef __attribute__((ext_vector_type(4))) float f32x4;    // MFMA C/D frag
typedef unsigned int u32;
typedef unsigned short u16;

#define MFMA(a,b,c) __builtin_amdgcn_mfma_f32_16x16x32_bf16((a),(b),(c),0,0,0)

__device__ __forceinline__ u16 f32_to_bf16_rtne(float f) {
  u32 b = __builtin_bit_cast(u32, f);
  b += 0x7FFFu + ((b >> 16) & 1u);
  return (u16)(b >> 16);
}
__device__ __forceinline__ u32 pk2bf(float a, float b) {
  u32 ua = __builtin_bit_cast(u32, a); ua += 0x7FFFu + ((ua >> 16) & 1u);
  u32 ub = __builtin_bit_cast(u32, b); ub += 0x7FFFu + ((ub >> 16) & 1u);
  return __builtin_amdgcn_perm(ub, ua, 0x07060302u);
}
__device__ __forceinline__ u32 pk2bf_rtz(float a, float b) {
  return __builtin_amdgcn_perm(__builtin_bit_cast(u32, b),
                               __builtin_bit_cast(u32, a), 0x07060302u);
}
__device__ __forceinline__ uint4 cvt8(uint4 lo, uint4 hi) {
  const float4 fl = __builtin_bit_cast(float4, lo);
  const float4 fh = __builtin_bit_cast(float4, hi);
  uint4 r;
  r.x = pk2bf(fl.x, fl.y); r.y = pk2bf(fl.z, fl.w);
  r.z = pk2bf(fh.x, fh.y); r.w = pk2bf(fh.z, fh.w);
  return r;
}

// barriers
__device__ __forceinline__ void barrier_lgkm() {   // LDS drained; vmem stays in flight
  asm volatile("s_waitcnt lgkmcnt(0)\n\ts_barrier" ::: "memory");
}

// async global->LDS DMA, 16B/lane; LDS dest = wave-uniform base + lane*16B
typedef const __attribute__((address_space(1))) void* gas_ptr;
typedef __attribute__((address_space(3))) void* las_ptr;
__device__ __forceinline__ void gload_lds16(const void* g, void* l) {
  __builtin_amdgcn_global_load_lds((gas_ptr)g, (las_ptr)l, 16, 0, 0);
}

static constexpr float SL2E = 0.125f * 1.44269504f;  // 1/sqrt(dh) * log2(e)

// ---------------------------------------------------------------------------
// f32 -> bf16 casts: W q/k/v/o and x.
// ---------------------------------------------------------------------------
__global__ __launch_bounds__(256)
void cast_all(const float* __restrict__ wq, const float* __restrict__ wk,
              const float* __restrict__ wv, const float* __restrict__ wo,
              const float* __restrict__ x,
              u16* __restrict__ wqkv, u16* __restrict__ wob,
              u16* __restrict__ xb) {
  const size_t DD8 = (size_t)1024 * 1024 / 8;
  if (blockIdx.x < 2048) {
    const int m = blockIdx.x >> 9;
    const size_t i = ((size_t)(blockIdx.x & 511)) * 256 + threadIdx.x;
    const float* src = (m == 0) ? wq : (m == 1) ? wk : (m == 2) ? wv : wo;
    u16* dst = (m < 3) ? (wqkv + (size_t)m * DD8 * 8) : wob;
    const float4* s = (const float4*)src + i * 2;
    ((uint4*)dst)[i] = cvt8(__builtin_bit_cast(uint4, s[0]),
                            __builtin_bit_cast(uint4, s[1]));
  } else {
    const size_t i = ((size_t)(blockIdx.x - 2048)) * 256 + threadIdx.x;
    const float4* s = (const float4*)x + i * 2;
    ((uint4*)xb)[i] = cvt8(__builtin_bit_cast(uint4, s[0]),
                           __builtin_bit_cast(uint4, s[1]));
  }
}

// ---------------------------------------------------------------------------
// QKV GEMM: 2-phase, BM=128 x BN=256, BK=64, 512 thr = 8 waves (2M x 4N),
// per-wave 64x64, acc[4][4].  LDS 96 KiB double-buffered, gload_lds staging,
// counted vmcnt(4) at tile boundary.  Best measured QKV: 75.4 us (R4).
// ---------------------------------------------------------------------------
__global__ __launch_bounds__(512, 2)
void gemm_qkv(const bf16* __restrict__ A, const bf16* __restrict__ W,
              const float* __restrict__ b0, const float* __restrict__ b1,
              const float* __restrict__ b2, u16* __restrict__ o0,
              u16* __restrict__ o1, u16* __restrict__ o2,
              int M, int N, int K)
{
  __shared__ __align__(16) bf16 AsB[2][128 * 64];
  __shared__ __align__(16) bf16 BsB[2][256 * 64];

  const int nwg = gridDim.x * gridDim.y;   // 768 (%8 == 0)
  const int raw = blockIdx.y * gridDim.x + blockIdx.x;
  const int vwg = (raw & 7) * (nwg >> 3) + (raw >> 3);
  const int NT  = gridDim.y;               // 12
  const int bx  = vwg / NT, by = vwg - bx * NT;
  const int m0  = bx * 128, n0 = by * 256;

  const int tid  = threadIdx.x;
  const int wv   = tid >> 6, lane = tid & 63;
  const int quad = lane >> 4, l16 = lane & 15;
  const int wm   = wv >> 2, wn = wv & 3;   // wave grid 2M x 4N
  const int r7   = l16 & 7;

  const int rr = tid >> 3, g = tid & 7;
  const int sg8 = (g ^ (rr & 7)) * 8;      // pre-swizzled source granule
  const bf16* aS = A + (size_t)(m0 + rr) * K + sg8;
  const bf16* wS = W + (size_t)(n0 + rr) * K + sg8;
  const int ldstW = wv * 512;              // wave-uniform LDS offset in chunk

#define STA8(buf, kt) do { \
    gload_lds16(aS + (size_t)(kt) * 64,                      &AsB[buf][ldstW]); \
    gload_lds16(aS + (size_t)64 * K + (size_t)(kt) * 64,     &AsB[buf][4096 + ldstW]); \
  } while (0)
#define STB8(buf, kt) do { \
    gload_lds16(wS + (size_t)(kt) * 64,                      &BsB[buf][ldstW]); \
    gload_lds16(wS + (size_t)64 * K + (size_t)(kt) * 64,     &BsB[buf][4096 + ldstW]); \
    gload_lds16(wS + (size_t)128 * K + (size_t)(kt) * 64,    &BsB[buf][8192 + ldstW]); \
    gload_lds16(wS + (size_t)192 * K + (size_t)(kt) * 64,    &BsB[buf][12288 + ldstW]); \
  } while (0)

  int aoff[4], boff[4];
#pragma unroll
  for (int mt = 0; mt < 4; ++mt) aoff[mt] = (wm * 64 + mt * 16 + l16) * 64;
#pragma unroll
  for (int nt = 0; nt < 4; ++nt) boff[nt] = (wn * 64 + nt * 16 + l16) * 64;
  const int k0o = (quad ^ r7) * 8;
  const int k1o = ((4 + quad) ^ r7) * 8;

  f32x4 acc[4][4] = {};
  bf16x8 bfr[4][2], afr[2][2];

  const int nk = K >> 6;   // 16

  // prologue: A(0), B(0) landed; B(1) in flight
  STA8(0, 0);
  STB8(0, 0);
  STB8(1, 1);
  asm volatile("s_waitcnt vmcnt(4)\n\ts_barrier" ::: "memory");

  for (int t = 0; t < nk; ++t) {
    const int c = t & 1;
    const bf16* Ac = AsB[c];
    const bf16* Bc = BsB[c];

    // phase 1: all-B + A-lo; stage A(t+1); MFMA mt0-1
#pragma unroll
    for (int nt = 0; nt < 4; ++nt) {
      bfr[nt][0] = *(const bf16x8*)(Bc + boff[nt] + k0o);
      bfr[nt][1] = *(const bf16x8*)(Bc + boff[nt] + k1o);
    }
#pragma unroll
    for (int mt = 0; mt < 2; ++mt) {
      afr[mt][0] = *(const bf16x8*)(Ac + aoff[mt] + k0o);
      afr[mt][1] = *(const bf16x8*)(Ac + aoff[mt] + k1o);
    }
    if (t + 1 < nk) STA8((t + 1) & 1, t + 1);
    asm volatile("s_barrier" ::: "memory");
    __builtin_amdgcn_s_setprio(1);
#pragma unroll
    for (int mt = 0; mt < 2; ++mt)
#pragma unroll
      for (int nt = 0; nt < 4; ++nt) {
        acc[mt][nt] = MFMA(afr[mt][0], bfr[nt][0], acc[mt][nt]);
        acc[mt][nt] = MFMA(afr[mt][1], bfr[nt][1], acc[mt][nt]);
      }
    __builtin_amdgcn_s_setprio(0);
    asm volatile("s_waitcnt lgkmcnt(0)\n\ts_barrier" ::: "memory");

    // phase 2: A-hi; stage B(t+2); MFMA mt2-3
#pragma unroll
    for (int mt = 0; mt < 2; ++mt) {
      afr[mt][0] = *(const bf16x8*)(Ac + aoff[mt + 2] + k0o);
      afr[mt][1] = *(const bf16x8*)(Ac + aoff[mt + 2] + k1o);
    }
    if (t + 2 < nk) STB8(c, t + 2);
    asm volatile("s_barrier" ::: "memory");
    __builtin_amdgcn_s_setprio(1);
#pragma unroll
    for (int mt = 0; mt < 2; ++mt)
#pragma unroll
      for (int nt = 0; nt < 4; ++nt) {
        acc[mt + 2][nt] = MFMA(afr[mt][0], bfr[nt][0], acc[mt + 2][nt]);
        acc[mt + 2][nt] = MFMA(afr[mt][1], bfr[nt][1], acc[mt + 2][nt]);
      }
    __builtin_amdgcn_s_setprio(0);
    if (t + 1 < nk) {
      if (t + 2 < nk)
        asm volatile("s_waitcnt vmcnt(4) lgkmcnt(0)\n\ts_barrier" ::: "memory");
      else
        asm volatile("s_waitcnt vmcnt(0) lgkmcnt(0)\n\ts_barrier" ::: "memory");
    }
  }
#undef STA8
#undef STB8

  // epilogue: C/D layout col = lane&15, row = quad*4 + reg
  const int band = n0 >> 10;
  const float* bias = (band == 0) ? b0 : (band == 1) ? b1 : b2;
#pragma unroll
  for (int nt = 0; nt < 4; ++nt) {
    const int col = n0 + wn * 64 + nt * 16 + l16;
    const int cl  = col & 1023;
    const float bv = bias[cl];
#pragma unroll
    for (int mt = 0; mt < 4; ++mt) {
      const int rbase = m0 + wm * 64 + mt * 16 + quad * 4;
      if (band == 2) {
        const int hh = cl >> 6, dd = cl & 63;
        const int bb = rbase >> 12, tl = rbase & 4095;
        u16* dst = o2 + ((size_t)((bb * 16 + hh) * 64 + dd)) * 4096 + tl;
        uint2 pk;
        pk.x = pk2bf(acc[mt][nt][0] + bv, acc[mt][nt][1] + bv);
        pk.y = pk2bf(acc[mt][nt][2] + bv, acc[mt][nt][3] + bv);
        *(uint2*)dst = pk;
      } else {
        u16* dst = (band == 0) ? o0 : o1;
        const float sc = (band == 0) ? SL2E : 1.0f;
#pragma unroll
        for (int r = 0; r < 4; ++r)
          dst[(size_t)(rbase + r) * 1024 + cl] =
              f32_to_bf16_rtne((acc[mt][nt][r] + bv) * sc);
      }
    }
  }
}

// ---------------------------------------------------------------------------
// Out-projection: 128x128 GEMM, m97 structure (gload_lds + __syncthreads),
// 512 blocks, 32 KiB LDS -> multiple blocks/CU.  Best measured out-proj
// (R1 composition: remainder 150.9 vs 169.3 with the 256-block variant).
// ---------------------------------------------------------------------------
__global__ __launch_bounds__(256)
void gemm_out(const bf16* __restrict__ A, const bf16* __restrict__ W,
              const float* __restrict__ bias, float* __restrict__ out,
              int M, int N, int K)
{
  __shared__ bf16 As[128 * 64];
  __shared__ bf16 Bs[128 * 64];

  const int tid  = threadIdx.x;
  const int wave = tid >> 6, lane = tid & 63;
  const int quad = lane >> 4, l16 = lane & 15;
  const int wm   = wave >> 1, wn  = wave & 1;
  const int m0   = blockIdx.x * 128, n0 = blockIdx.y * 128;

  const int srow = lane >> 3;
  const int sg   = lane & 7;
  const size_t rgs = (size_t)8 * K;
  const bf16* aSrc = A + (size_t)(m0 + wave * 32 + srow) * K + ((sg ^ srow) * 8);
  const bf16* wSrc = W + (size_t)(n0 + wave * 32 + srow) * K + ((sg ^ srow) * 8);
  bf16* aB = As + wave * 32 * 64;
  bf16* wB = Bs + wave * 32 * 64;

  const int niter = K >> 6;

  f32x4 acc[4][4] = {};

  const int arow[4] = { (wm * 64 + 0 * 16 + l16) * 64, (wm * 64 + 1 * 16 + l16) * 64,
                        (wm * 64 + 2 * 16 + l16) * 64, (wm * 64 + 3 * 16 + l16) * 64 };
  const int brow[4] = { (wn * 64 + 0 * 16 + l16) * 64, (wn * 64 + 1 * 16 + l16) * 64,
                        (wn * 64 + 2 * 16 + l16) * 64, (wn * 64 + 3 * 16 + l16) * 64 };
  const int r7 = l16 & 7;

  for (int t = 0; t < niter; ++t) {
    gload_lds16(aSrc,            aB);
    gload_lds16(aSrc + rgs,      aB + 512);
    gload_lds16(aSrc + 2 * rgs,  aB + 1024);
    gload_lds16(aSrc + 3 * rgs,  aB + 1536);
    gload_lds16(wSrc,            wB);
    gload_lds16(wSrc + rgs,      wB + 512);
    gload_lds16(wSrc + 2 * rgs,  wB + 1024);
    gload_lds16(wSrc + 3 * rgs,  wB + 1536);
    aSrc += 64; wSrc += 64;
    __syncthreads();

#pragma unroll
    for (int kk = 0; kk < 2; ++kk) {
      bf16x8 af[4], bw[4];
#pragma unroll
      for (int mt = 0; mt < 4; ++mt)
        af[mt] = *(const bf16x8*)(As + arow[mt] + (((kk * 4 + quad) ^ r7) * 8));
#pragma unroll
      for (int nt = 0; nt < 4; ++nt)
        bw[nt] = *(const bf16x8*)(Bs + brow[nt] + (((kk * 4 + quad) ^ r7) * 8));
#pragma unroll
      for (int mt = 0; mt < 4; ++mt)
#pragma unroll
        for (int nt = 0; nt < 4; ++nt)
          acc[mt][nt] = MFMA(af[mt], bw[nt], acc[mt][nt]);
    }
    if (t + 1 < niter) __syncthreads();
  }

#pragma unroll
  for (int nt = 0; nt < 4; ++nt) {
    const int col = n0 + wn * 64 + nt * 16 + l16;
    const float bv = bias[col & 1023];
#pragma unroll
    for (int mt = 0; mt < 4; ++mt) {
      const int rbase = m0 + wm * 64 + mt * 16 + quad * 4;
#pragma unroll
      for (int r = 0; r < 4; ++r)
        out[(size_t)(rbase + r) * N + col] = acc[mt][nt][r] + bv;
    }
  }
}

// ---------------------------------------------------------------------------
// Sliding-window attention, S^T formulation, fixed-max softmax,
// double-buffered K/V LDS, one lgkm barrier per tile (original, proven).
// ---------------------------------------------------------------------------
__global__ __launch_bounds__(256)
void attn_swin(const bf16* __restrict__ qb, const bf16* __restrict__ kb,
               const bf16* __restrict__ vtb, u16* __restrict__ ctx)
{
  __shared__ __align__(16) bf16 Ks[2][64 * 72];
  __shared__ __align__(16) bf16 Vts[2][64 * 72];

  int bid = blockIdx.x;
  const int g  = bid & 255, qt = bid >> 8;
  const int h  = g & 15, c = (g >> 4) & 7, b = g >> 7;

  const int tid  = threadIdx.x;
  const int w    = tid >> 6, lane = tid & 63;
  const int quad = lane >> 4, l16 = lane & 15;

  const int tq0  = c * 512 + qt * 128;
  const int hoff = h * 64;
  const int kstart = (c == 0) ? 0 : (c - 1) * 512;
  const int nkt    = (c == 0) ? 8 : 16;

  bf16x8 qf[2][2];
#pragma unroll
  for (int u = 0; u < 2; ++u) {
    const bf16* qr = qb + ((size_t)(b * 4096 + tq0 + w * 32 + u * 16 + l16)) * 1024 + hoff;
    qf[u][0] = *(const bf16x8*)(qr + quad * 8);
    qf[u][1] = *(const bf16x8*)(qr + 32 + quad * 8);
  }

  const int m    = tid >> 2;
  const int cseg = (tid & 3) * 16;
  const int sig  = (((m >> 4) & 1) << 5) | (((m >> 2) & 3) << 3)
                 | (((m >> 5) & 1) << 2) | (m & 3);
  const bf16* kgp = kb + ((size_t)(b * 4096 + kstart + sig)) * 1024 + hoff + cseg;
  const bf16* vgp = vtb + ((size_t)((b * 16 + h) * 64 + m)) * 4096 + kstart + cseg;
  const int soff = m * 72 + cseg;

  float l_i[2] = {0.f, 0.f};
  f32x4 o[2][4] = {};

  uint4 ka0 = *(const uint4*)(kgp), ka1 = *(const uint4*)(kgp + 8);
  uint4 va0 = *(const uint4*)(vgp), va1 = *(const uint4*)(vgp + 8);
  kgp += (size_t)64 * 1024; vgp += 64;
  *(uint4*)(Ks[0] + soff) = ka0; *(uint4*)(Ks[0] + soff + 8) = ka1;
  *(uint4*)(Vts[0] + soff) = va0; *(uint4*)(Vts[0] + soff + 8) = va1;
  ka0 = *(const uint4*)(kgp); ka1 = *(const uint4*)(kgp + 8);
  va0 = *(const uint4*)(vgp); va1 = *(const uint4*)(vgp + 8);
  kgp += (size_t)64 * 1024; vgp += 64;
  barrier_lgkm();

  typedef union { u32 d[4]; bf16x8 v; } fragu;

  auto compute = [&](const bf16* ksb, const bf16* vtsb) {
    f32x4 s[2][4] = {};
#pragma unroll
    for (int kt = 0; kt < 4; ++kt) {
      const bf16* kr = ksb + (kt * 16 + l16) * 72;
      bf16x8 kf0 = *(const bf16x8*)(kr + quad * 8);
      bf16x8 kf1 = *(const bf16x8*)(kr + 32 + quad * 8);
      s[0][kt] = MFMA(kf0, qf[0][0], s[0][kt]);
      s[0][kt] = MFMA(kf1, qf[0][1], s[0][kt]);
      s[1][kt] = MFMA(kf0, qf[1][0], s[1][kt]);
      s[1][kt] = MFMA(kf1, qf[1][1], s[1][kt]);
    }
    fragu pf[2][2];
#pragma unroll
    for (int u = 0; u < 2; ++u) {
      float rs = 0.f;
#pragma unroll
      for (int kt = 0; kt < 4; ++kt)
#pragma unroll
        for (int r = 0; r < 4; ++r) {
          const float p = __builtin_amdgcn_exp2f(s[u][kt][r]);
          s[u][kt][r] = p;
          rs += p;
        }
      rs += __shfl_xor(rs, 16);
      rs += __shfl_xor(rs, 32);
      l_i[u] += rs;
#pragma unroll
      for (int hh = 0; hh < 2; ++hh)
#pragma unroll
        for (int dw = 0; dw < 4; ++dw) {
          const int kt = 2 * (dw >> 1) + hh, r0 = 2 * (dw & 1);
          pf[u][hh].d[dw] = pk2bf_rtz(s[u][kt][r0], s[u][kt][r0 + 1]);
        }
    }
#pragma unroll
    for (int dt = 0; dt < 4; ++dt) {
      const bf16* vr = vtsb + (dt * 16 + l16) * 72;
      bf16x8 vf0 = *(const bf16x8*)(vr + quad * 8);
      bf16x8 vf1 = *(const bf16x8*)(vr + 32 + quad * 8);
      o[0][dt] = MFMA(vf0, pf[0][0].v, o[0][dt]);
      o[0][dt] = MFMA(vf1, pf[0][1].v, o[0][dt]);
      o[1][dt] = MFMA(vf0, pf[1][0].v, o[1][dt]);
      o[1][dt] = MFMA(vf1, pf[1][1].v, o[1][dt]);
    }
  };

  for (int t = 0; t < nkt; t += 2) {
    *(uint4*)(Ks[1] + soff) = ka0; *(uint4*)(Ks[1] + soff + 8) = ka1;
    *(uint4*)(Vts[1] + soff) = va0; *(uint4*)(Vts[1] + soff + 8) = va1;
    if (t + 2 < nkt) {
      ka0 = *(const uint4*)(kgp); ka1 = *(const uint4*)(kgp + 8);
      va0 = *(const uint4*)(vgp); va1 = *(const uint4*)(vgp + 8);
      kgp += (size_t)64 * 1024; vgp += 64;
    }
    compute(Ks[0], Vts[0]);
    barrier_lgkm();

    if (t + 2 < nkt) {
      *(uint4*)(Ks[0] + soff) = ka0; *(uint4*)(Ks[0] + soff + 8) = ka1;
      *(uint4*)(Vts[0] + soff) = va0; *(uint4*)(Vts[0] + soff + 8) = va1;
      if (t + 3 < nkt) {
        ka0 = *(const uint4*)(kgp); ka1 = *(const uint4*)(kgp + 8);
        va0 = *(const uint4*)(vgp); va1 = *(const uint4*)(vgp + 8);
        kgp += (size_t)64 * 1024; vgp += 64;
      }
    }
    compute(Ks[1], Vts[1]);
    barrier_lgkm();
  }

#pragma unroll
  for (int u = 0; u < 2; ++u) {
    const float inv = 1.0f / l_i[u];
    const int qrow = tq0 + w * 32 + u * 16 + l16;
    u16* crow = ctx + ((size_t)(b * 4096 + qrow)) * 1024 + hoff;
#pragma unroll
    for (int dt = 0; dt < 4; ++dt) {
      uint2 pk;
      pk.x = pk2bf(o[u][dt][0] * inv, o[u][dt][1] * inv);
      pk.y = pk2bf(o[u][dt][2] * inv, o[u][dt][3] * inv);
      *(uint2*)(crow + dt * 16 + quad * 4) = pk;
    }
  }
}

// ---------------------------------------------------------------------------
extern "C" void kernel_launch(void* const* d_in, const int* in_sizes, int n_in,
                              void* d_out, int out_size, void* d_ws, size_t ws_size,
                              hipStream_t stream) {
  const float* x  = (const float*)d_in[0];
  const float* Wq = (const float*)d_in[1];
  const float* bq = (const float*)d_in[2];
  const float* Wk = (const float*)d_in[3];
  const float* bk = (const float*)d_in[4];
  const float* Wv = (const float*)d_in[5];
  const float* bv = (const float*)d_in[6];
  const float* Wo = (const float*)d_in[7];
  const float* bo = (const float*)d_in[8];

  const size_t MD = (size_t)8192 * 1024;   // [B*L, D] elements
  const size_t DD = (size_t)1024 * 1024;   // [D, D] elements

  char* ws = (char*)d_ws;
  u16*  Wqkvb = (u16*)ws;                     ws += 3 * DD * 2;
  u16*  Wob   = (u16*)ws;                     ws += DD * 2;
  u16*  qbuf  = (u16*)ws;                     ws += MD * 2;
  u16*  kbuf  = (u16*)ws;                     ws += MD * 2;
  u16*  vtb   = (u16*)ws;                     ws += MD * 2;
  u16*  ctx   = (u16*)ws;                     // + MD*2  (~72 MB total)

  // xb aliases ctx: dead after the QKV GEMM; attn writes ctx afterwards.
  u16* xb = ctx;

  cast_all<<<dim3(6144), dim3(256), 0, stream>>>(Wq, Wk, Wv, Wo, x,
                                                 Wqkvb, Wob, xb);

  gemm_qkv<<<dim3(64, 12), dim3(512), 0, stream>>>(
      (const bf16*)xb, (const bf16*)Wqkvb, bq, bk, bv,
      qbuf, kbuf, vtb, 8192, 3072, 1024);

  attn_swin<<<dim3(1024), dim3(256), 0, stream>>>(
      (const bf16*)qbuf, (const bf16*)kbuf, (const bf16*)vtb, ctx);

  gemm_out<<<dim3(64, 8), dim3(256), 0, stream>>>(
      (const bf16*)ctx, (const bf16*)Wob, bo, (float*)d_out, 8192, 1024, 1024);
}